// Round 5
// baseline (277.145 us; speedup 1.0000x reference)
//
#include <hip/hip_runtime.h>
#include <math.h>

// TimestepNorm forward, prefix-sum reformulation:
//   c_t   = C0 + #valid<=t
//   M_t   = C0*pm + sum(valid*x)             -> mean = M/c
//   var_t = (V2 + sum(valid*x^2) - M_t^2/c_t)/c_t,  V2 = C0*(exp(plv)+pm^2)
//
// v6 = v5 with ONE change (controlled A/B): pass3's x loads are back to
// regular cached loads. v5 used nontemporal loads on the theory "x is dead
// after pass3" — but pass3's x re-read is supposed to HIT the L3 lines that
// pass1 filled; if the nt policy bypasses/doesn't-allocate L3, the re-read
// goes to HBM (131 MB) and pass3 stays ~60-70 us. The nt STORE on y is the
// proven win (284.6 -> 276.4: no write-allocate, keeps x resident) and is
// kept. 3-pass structure: NC=512 => CT=16, 4096 blocks x 128 thr,
// 32 waves/CU.

#define T_DIM 8192
#define B_DIM 8
#define D_DIM 512
#define BD    (B_DIM * D_DIM)   // 4096 floats per time row
#define BD4   (BD / 4)          // 1024 float4 per time row
#define D4    (D_DIM / 4)       // 128 float4 per (t,b)
#define C0    2.0f              // PRIOR_COUNT
#define EPS   1e-5f

typedef float nt_f4 __attribute__((ext_vector_type(4)));

__device__ __forceinline__ float4 f4add(float4 a, float4 b) {
  return make_float4(a.x + b.x, a.y + b.y, a.z + b.z, a.w + b.w);
}
__device__ __forceinline__ float4 f4sub(float4 a, float4 b) {
  return make_float4(a.x - b.x, a.y - b.y, a.z - b.z, a.w - b.w);
}

__device__ __forceinline__ void ntstore4(float4 v, float4* p) {
  nt_f4 t = {v.x, v.y, v.z, v.w};
  __builtin_nontemporal_store(t, (nt_f4*)p);
}

// ---------------- pass1: per-chunk partial sums ----------------
template <int NC>
__global__ __launch_bounds__(128) void ts_pass1(
    const float* __restrict__ x, const unsigned char* __restrict__ mask,
    float* __restrict__ s1p, float* __restrict__ s2p, float* __restrict__ cnt) {
  constexpr int CT = T_DIM / NC;
  constexpr int NW = CT / 8;
  const int chunk = blockIdx.x;
  const int b     = blockIdx.y;
  const int tid   = threadIdx.x;
  const int t0    = chunk * CT;
  const float4* xp = (const float4*)x;

  unsigned long long mw[NW];
  const unsigned long long* m8 =
      (const unsigned long long*)(mask + b * T_DIM + t0);
#pragma unroll
  for (int j = 0; j < NW; ++j) mw[j] = m8[j];

  float4 s1 = make_float4(0.f, 0.f, 0.f, 0.f);
  float4 s2 = make_float4(0.f, 0.f, 0.f, 0.f);
  float c = 0.f;
#pragma unroll 8
  for (int i = 0; i < CT; ++i) {
    float valid = ((mw[i >> 3] >> ((i & 7) * 8)) & 0xffULL) ? 0.f : 1.f;
    float4 v = xp[(t0 + i) * BD4 + b * D4 + tid];
    c += valid;
    s1.x += valid * v.x; s2.x += valid * v.x * v.x;
    s1.y += valid * v.y; s2.y += valid * v.y * v.y;
    s1.z += valid * v.z; s2.z += valid * v.z * v.z;
    s1.w += valid * v.w; s2.w += valid * v.w * v.w;
  }
  const int pidx = chunk * BD4 + b * D4 + tid;
  ((float4*)s1p)[pidx] = s1;
  ((float4*)s2p)[pidx] = s2;
  if (tid == 0) cnt[chunk * B_DIM + b] = c;
}

// ---------------- pass2: wave-parallel exclusive scan over chunks ----------
// One wave per column. s1p/s2p: 2*BD4 float4-columns of length NC (stride BD4
// float4). cnt: B_DIM scalar columns of length NC (stride B_DIM). In-place:
// each column is owned by exactly one wave.
template <int NC>
__global__ __launch_bounds__(256) void ts_pass2(
    float* __restrict__ s1p, float* __restrict__ s2p, float* __restrict__ cnt) {
  constexpr int KPL = NC / 64;  // chunks per lane
  const int wid  = (blockIdx.x * 256 + threadIdx.x) >> 6;
  const int lane = threadIdx.x & 63;

  if (wid < 2 * BD4) {
    float4* base = (float4*)(wid < BD4 ? s1p : s2p);
    const int col = wid & (BD4 - 1);
    float4 vals[KPL];
#pragma unroll
    for (int j = 0; j < KPL; ++j)
      vals[j] = base[(lane * KPL + j) * BD4 + col];
#pragma unroll
    for (int j = 1; j < KPL; ++j) vals[j] = f4add(vals[j], vals[j - 1]);
    float4 tot = vals[KPL - 1];
    float4 inc = tot;
#pragma unroll
    for (int off = 1; off < 64; off <<= 1) {
      float4 o;
      o.x = __shfl_up(inc.x, off);
      o.y = __shfl_up(inc.y, off);
      o.z = __shfl_up(inc.z, off);
      o.w = __shfl_up(inc.w, off);
      if (lane >= off) inc = f4add(inc, o);
    }
    float4 excl = f4sub(inc, tot);  // exclusive prefix of this lane's segment
#pragma unroll
    for (int j = KPL - 1; j >= 1; --j)
      base[(lane * KPL + j) * BD4 + col] = f4add(excl, vals[j - 1]);
    base[(lane * KPL) * BD4 + col] = excl;
  } else if (wid < 2 * BD4 + B_DIM) {
    const int b = wid - 2 * BD4;
    float vals[KPL];
#pragma unroll
    for (int j = 0; j < KPL; ++j) vals[j] = cnt[(lane * KPL + j) * B_DIM + b];
#pragma unroll
    for (int j = 1; j < KPL; ++j) vals[j] += vals[j - 1];
    float tot = vals[KPL - 1];
    float inc = tot;
#pragma unroll
    for (int off = 1; off < 64; off <<= 1) {
      float o = __shfl_up(inc, off);
      if (lane >= off) inc += o;
    }
    float excl = inc - tot;
#pragma unroll
    for (int j = KPL - 1; j >= 1; --j)
      cnt[(lane * KPL + j) * B_DIM + b] = excl + vals[j - 1];
    cnt[lane * KPL * B_DIM + b] = excl;
  }
}

// ---------------- pass3: replay chunk with y epilogue ----------------
template <int NC>
__global__ __launch_bounds__(128) void ts_pass3(
    const float* __restrict__ x, const unsigned char* __restrict__ mask,
    const float* __restrict__ pm, const float* __restrict__ plv,
    const float* __restrict__ w, const float* __restrict__ bias,
    const float* __restrict__ e1, const float* __restrict__ e2,
    const float* __restrict__ ecnt, float* __restrict__ out) {
  constexpr int CT = T_DIM / NC;
  constexpr int NW = CT / 8;
  const int chunk = blockIdx.x;
  const int b     = blockIdx.y;
  const int tid   = threadIdx.x;
  const int t0    = chunk * CT;
  const int col   = b * D4 + tid;

  // Exclusive chunk prefix: O(1) loads (pass2 already scanned).
  float4 S1 = ((const float4*)e1)[chunk * BD4 + col];
  float4 S2 = ((const float4*)e2)[chunk * BD4 + col];
  float c = C0 + ecnt[chunk * B_DIM + b];

  float4 pm4 = ((const float4*)pm)[tid];
  float4 lv4 = ((const float4*)plv)[tid];
  float4 g4  = ((const float4*)w)[tid];
  float4 be4 = ((const float4*)bias)[tid];
  g4.x += 1.f; g4.y += 1.f; g4.z += 1.f; g4.w += 1.f;
  float M0x = C0 * pm4.x, M0y = C0 * pm4.y, M0z = C0 * pm4.z, M0w = C0 * pm4.w;
  float V2x = C0 * (__expf(lv4.x) + pm4.x * pm4.x);
  float V2y = C0 * (__expf(lv4.y) + pm4.y * pm4.y);
  float V2z = C0 * (__expf(lv4.z) + pm4.z * pm4.z);
  float V2w = C0 * (__expf(lv4.w) + pm4.w * pm4.w);

  unsigned long long mw[NW];
  const unsigned long long* m8 =
      (const unsigned long long*)(mask + b * T_DIM + t0);
#pragma unroll
  for (int j = 0; j < NW; ++j) mw[j] = m8[j];

  const float4* xp = (const float4*)x;
  float4* op = (float4*)out;

#pragma unroll 4
  for (int i = 0; i < CT; ++i) {
    float valid = ((mw[i >> 3] >> ((i & 7) * 8)) & 0xffULL) ? 0.f : 1.f;
    const int xi = (t0 + i) * BD4 + col;
    // Regular cached load: hits the L3 lines pass1 filled (v5's nt load
    // plausibly bypassed L3 and forced a full HBM re-read).
    float4 v = xp[xi];
    c += valid;
    float rc = __builtin_amdgcn_rcpf(c);
    float4 y;
    {
      S1.x += valid * v.x; S2.x += valid * v.x * v.x;
      float M = M0x + S1.x;
      float mean = M * rc;
      float var = (V2x + S2.x - M * M * rc) * rc;
      y.x = (v.x - mean) * __builtin_amdgcn_rsqf(var + EPS) * g4.x + be4.x;
    }
    {
      S1.y += valid * v.y; S2.y += valid * v.y * v.y;
      float M = M0y + S1.y;
      float mean = M * rc;
      float var = (V2y + S2.y - M * M * rc) * rc;
      y.y = (v.y - mean) * __builtin_amdgcn_rsqf(var + EPS) * g4.y + be4.y;
    }
    {
      S1.z += valid * v.z; S2.z += valid * v.z * v.z;
      float M = M0z + S1.z;
      float mean = M * rc;
      float var = (V2z + S2.z - M * M * rc) * rc;
      y.z = (v.z - mean) * __builtin_amdgcn_rsqf(var + EPS) * g4.z + be4.z;
    }
    {
      S1.w += valid * v.w; S2.w += valid * v.w * v.w;
      float M = M0w + S1.w;
      float mean = M * rc;
      float var = (V2w + S2.w - M * M * rc) * rc;
      y.w = (v.w - mean) * __builtin_amdgcn_rsqf(var + EPS) * g4.w + be4.w;
    }
    // y never re-read: nontemporal store (no write-allocate; keeps x in L3).
    ntstore4(y, &op[xi]);
  }
}

// ---------------- launch ----------------
template <int NC>
static void run_3pass(const float* x, const unsigned char* mask,
                      const float* pm, const float* plv, const float* w,
                      const float* bias, float* out, float* ws,
                      hipStream_t stream) {
  float* s1p = ws;
  float* s2p = s1p + (size_t)NC * BD;
  float* cnt = s2p + (size_t)NC * BD;
  dim3 grid(NC, B_DIM);
  ts_pass1<NC><<<grid, 128, 0, stream>>>(x, mask, s1p, s2p, cnt);
  const int scan_waves = 2 * BD4 + B_DIM;        // 2056
  const int scan_blocks = (scan_waves + 3) / 4;  // 514 blocks of 4 waves
  ts_pass2<NC><<<scan_blocks, 256, 0, stream>>>(s1p, s2p, cnt);
  ts_pass3<NC><<<grid, 128, 0, stream>>>(x, mask, pm, plv, w, bias, s1p, s2p,
                                         cnt, out);
}

extern "C" void kernel_launch(void* const* d_in, const int* in_sizes, int n_in,
                              void* d_out, int out_size, void* d_ws,
                              size_t ws_size, hipStream_t stream) {
  const float* x    = (const float*)d_in[0];
  const float* pm   = (const float*)d_in[1];
  const float* plv  = (const float*)d_in[2];
  const float* w    = (const float*)d_in[3];
  const float* bias = (const float*)d_in[4];
  const unsigned char* mask = (const unsigned char*)d_in[5];
  float* out = (float*)d_out;
  float* ws  = (float*)d_ws;

  const size_t need512 = ((size_t)2 * 512 * BD + 512 * B_DIM) * sizeof(float);
  const size_t need256 = ((size_t)2 * 256 * BD + 256 * B_DIM) * sizeof(float);
  if (ws_size >= need512) {
    run_3pass<512>(x, mask, pm, plv, w, bias, out, ws, stream);
  } else if (ws_size >= need256) {
    run_3pass<256>(x, mask, pm, plv, w, bias, out, ws, stream);
  } else {
    run_3pass<128>(x, mask, pm, plv, w, bias, out, ws, stream);
  }
}